// Round 1
// baseline (7020.700 us; speedup 1.0000x reference)
//
#include <hip/hip_runtime.h>

static constexpr int kS  = 13294;
static constexpr int kB  = 2;
static constexpr int kBS = kB * kS;     // 26588
static constexpr int kC  = 256;
static constexpr int kH  = 8;
static constexpr int kNQ = 300;
static constexpr int kFF = 1024;
static constexpr int kNL = 6;

// ---------------- GEMM: out[M,N] = act(A[M,K] @ W[N,K]^T + bias[N]) ----------------
// BM=BN=64, BK=16, 256 threads, 4x4 per thread. N must be a multiple of 64, K of 16.
template<int ACT>
__global__ __launch_bounds__(256) void gemm_bias(
    const float* __restrict__ A, const float* __restrict__ Wt,
    const float* __restrict__ bias, float* __restrict__ out,
    int M, int N, int K) {
  __shared__ float As[16][68];
  __shared__ float Bs[16][68];
  const int t = threadIdx.x;
  const int tx = t & 15, ty = t >> 4;
  const int m0 = blockIdx.y << 6, n0 = blockIdx.x << 6;
  const int lr = t >> 2;          // 0..63
  const int lk = (t & 3) << 2;    // 0,4,8,12
  const int am = m0 + lr;
  const float* Ap = A + (size_t)am * K + lk;
  const float* Wp = Wt + (size_t)(n0 + lr) * K + lk;
  float acc[4][4] = {};
  for (int k0 = 0; k0 < K; k0 += 16) {
    float4 av = make_float4(0.f, 0.f, 0.f, 0.f);
    if (am < M) av = *(const float4*)(Ap + k0);
    const float4 wv = *(const float4*)(Wp + k0);
    __syncthreads();
    As[lk + 0][lr] = av.x; As[lk + 1][lr] = av.y; As[lk + 2][lr] = av.z; As[lk + 3][lr] = av.w;
    Bs[lk + 0][lr] = wv.x; Bs[lk + 1][lr] = wv.y; Bs[lk + 2][lr] = wv.z; Bs[lk + 3][lr] = wv.w;
    __syncthreads();
#pragma unroll
    for (int kk = 0; kk < 16; ++kk) {
      const float4 a4 = *(const float4*)&As[kk][ty << 2];
      const float4 b4 = *(const float4*)&Bs[kk][tx << 2];
      const float a[4] = {a4.x, a4.y, a4.z, a4.w};
      const float b[4] = {b4.x, b4.y, b4.z, b4.w};
#pragma unroll
      for (int i = 0; i < 4; ++i)
#pragma unroll
        for (int j = 0; j < 4; ++j)
          acc[i][j] = fmaf(a[i], b[j], acc[i][j]);
    }
  }
  const int n = n0 + (tx << 2);
  const float4 bi = *(const float4*)(bias + n);
#pragma unroll
  for (int i = 0; i < 4; ++i) {
    const int m = m0 + (ty << 2) + i;
    if (m < M) {
      float4 o;
      o.x = acc[i][0] + bi.x;
      o.y = acc[i][1] + bi.y;
      o.z = acc[i][2] + bi.z;
      o.w = acc[i][3] + bi.w;
      if (ACT == 1) {
        o.x = fmaxf(o.x, 0.f); o.y = fmaxf(o.y, 0.f);
        o.z = fmaxf(o.z, 0.f); o.w = fmaxf(o.w, 0.f);
      }
      *(float4*)(out + (size_t)m * N + n) = o;
    }
  }
}

// ---------------- q = memory + pos_flatten + level_embed[level(s)] ----------------
__global__ void enc_q_k(const float* __restrict__ mem, const float* __restrict__ pos,
                        const float* __restrict__ lev, float* __restrict__ q, int n4) {
  int i = blockIdx.x * 256 + threadIdx.x;
  if (i >= n4) return;
  int c4 = i & 63;
  int row = i >> 6;            // b*S + s
  int s = row % kS;
  int l = (s < 10000) ? 0 : (s < 12500) ? 1 : (s < 13125) ? 2 : 3;
  float4 m = ((const float4*)mem)[i];
  float4 p = ((const float4*)pos)[i];
  float4 lv = ((const float4*)(lev + l * kC))[c4];
  float4 o;
  o.x = m.x + p.x + lv.x; o.y = m.y + p.y + lv.y;
  o.z = m.z + p.z + lv.z; o.w = m.w + p.w + lv.w;
  ((float4*)q)[i] = o;
}

// ---------------- softmax over 16 contiguous values per thread ----------------
__global__ void softmax16_k(float* __restrict__ aw, int total) {
  int i = blockIdx.x * 256 + threadIdx.x;
  if (i >= total) return;
  float* p = aw + (size_t)i * 16;
  float v[16];
  float mx = -1e30f;
#pragma unroll
  for (int j = 0; j < 16; ++j) { v[j] = p[j]; mx = fmaxf(mx, v[j]); }
  float s = 0.f;
#pragma unroll
  for (int j = 0; j < 16; ++j) { v[j] = __expf(v[j] - mx); s += v[j]; }
  float inv = 1.f / s;
#pragma unroll
  for (int j = 0; j < 16; ++j) p[j] = v[j] * inv;
}

// ---------------- encoder reference points table refS[s][2] ----------------
__global__ void refs_k(float* __restrict__ refS) {
  int s = blockIdx.x * 256 + threadIdx.x;
  if (s >= kS) return;
  int st, W;
  if (s < 10000)      { st = 0;     W = 100; }
  else if (s < 12500) { st = 10000; W = 50; }
  else if (s < 13125) { st = 12500; W = 25; }
  else                { st = 13125; W = 13; }
  int idx = s - st;
  int y = idx / W;
  int x = idx - y * W;
  refS[s * 2 + 0] = (x + 0.5f) / (float)W;
  refS[s * 2 + 1] = (y + 0.5f) / (float)W;
}

// ---------------- MSDA bilinear sampling ----------------
// value:[B,S,H*32]  offs:[B,Mq,H,L,P,2]  aw:[B,Mq,H,L,P] (softmaxed)  refs:[Mq_or_S][2]
// out:[B,Mq,H*32]   group of 32 lanes per (b,q,h), lane = d
__global__ __launch_bounds__(256) void msda_sample_k(
    const float* __restrict__ value, const float* __restrict__ offs,
    const float* __restrict__ aw, const float* __restrict__ refs,
    float* __restrict__ out, int Mq) {
  const int g = threadIdx.x >> 5, lane = threadIdx.x & 31;
  const long gid = (long)blockIdx.x * 8 + g;
  const long bq = gid >> 3;
  const int h = (int)(gid & 7);
  if (bq >= (long)kB * Mq) return;
  const int b = (bq >= Mq) ? 1 : 0;
  const int qi = (int)(bq - (long)b * Mq);
  const float rx = refs[qi * 2 + 0];
  const float ry = refs[qi * 2 + 1];
  const float* op = offs + (bq * 8 + h) * 32;
  const float* ap = aw + (bq * 8 + h) * 16;
  const int starts[4] = {0, 10000, 12500, 13125};
  const int wtab[4] = {100, 50, 25, 13};
  float acc = 0.f;
#pragma unroll
  for (int l = 0; l < 4; ++l) {
    const int W = wtab[l];
    const float fW = (float)W;
    const float* vb = value + ((size_t)(b * kS + starts[l])) * 256 + h * 32 + lane;
#pragma unroll
    for (int p = 0; p < 4; ++p) {
      const float a = ap[l * 4 + p];
      const float px = rx * fW + op[(l * 4 + p) * 2 + 0] - 0.5f;
      const float py = ry * fW + op[(l * 4 + p) * 2 + 1] - 0.5f;
      const float fx = floorf(px), fy = floorf(py);
      const float wx = px - fx, wy = py - fy;
      const int x0 = (int)fx, y0 = (int)fy;
      const bool xa = (x0 >= 0) && (x0 < W);
      const bool xb = (x0 + 1 >= 0) && (x0 + 1 < W);
      const bool ya = (y0 >= 0) && (y0 < W);
      const bool yb = (y0 + 1 >= 0) && (y0 + 1 < W);
      float v00 = 0.f, v01 = 0.f, v10 = 0.f, v11 = 0.f;
      if (ya && xa) v00 = vb[(y0 * W + x0) * 256];
      if (ya && xb) v01 = vb[(y0 * W + x0 + 1) * 256];
      if (yb && xa) v10 = vb[((y0 + 1) * W + x0) * 256];
      if (yb && xb) v11 = vb[((y0 + 1) * W + x0 + 1) * 256];
      acc += a * ((1.f - wy) * ((1.f - wx) * v00 + wx * v01) +
                  wy * ((1.f - wx) * v10 + wx * v11));
    }
  }
  out[(bq * 8 + h) * 32 + lane] = acc;
}

// ---------------- LayerNorm(x + y) * g + b, C = 256, one wave per row ----------------
__global__ __launch_bounds__(256) void ln_res_k(
    const float* __restrict__ x, const float* __restrict__ y,
    const float* __restrict__ g, const float* __restrict__ be,
    float* __restrict__ out, int rows) {
  const int wid = threadIdx.x >> 6;
  const int lane = threadIdx.x & 63;
  const int row = blockIdx.x * 4 + wid;
  if (row >= rows) return;
  const float4 a = ((const float4*)(x + (size_t)row * 256))[lane];
  const float4 b = ((const float4*)(y + (size_t)row * 256))[lane];
  const float v0 = a.x + b.x, v1 = a.y + b.y, v2 = a.z + b.z, v3 = a.w + b.w;
  float s = v0 + v1 + v2 + v3;
  float s2 = v0 * v0 + v1 * v1 + v2 * v2 + v3 * v3;
#pragma unroll
  for (int off = 32; off; off >>= 1) {
    s += __shfl_xor(s, off);
    s2 += __shfl_xor(s2, off);
  }
  const float mean = s * (1.f / 256.f);
  const float var = s2 * (1.f / 256.f) - mean * mean;
  const float r = rsqrtf(var + 1e-5f);
  const float4 gg = ((const float4*)g)[lane];
  const float4 bb = ((const float4*)be)[lane];
  float4 o;
  o.x = (v0 - mean) * r * gg.x + bb.x;
  o.y = (v1 - mean) * r * gg.y + bb.y;
  o.z = (v2 - mean) * r * gg.z + bb.z;
  o.w = (v3 - mean) * r * gg.w + bb.w;
  ((float4*)(out + (size_t)row * 256))[lane] = o;
}

// ---------------- out[i] = a[i] + b[i % nb]  (float4-vectorized) ----------------
__global__ void add_bcast_k(const float* __restrict__ a, const float* __restrict__ b,
                            float* __restrict__ out, int n4, int nb4) {
  int i = blockIdx.x * 256 + threadIdx.x;
  if (i >= n4) return;
  const float4 av = ((const float4*)a)[i];
  const float4 bv = ((const float4*)b)[i % nb4];
  float4 o;
  o.x = av.x + bv.x; o.y = av.y + bv.y; o.z = av.z + bv.z; o.w = av.w + bv.w;
  ((float4*)out)[i] = o;
}

// ---------------- decoder init: split query_embed into qpos / tgt (bcast B) ----------------
__global__ void dec_init_k(const float* __restrict__ qe, float* __restrict__ tgt,
                           float* __restrict__ qposb) {
  int i = blockIdx.x * 256 + threadIdx.x;
  if (i >= kNQ * kC) return;
  int q = i >> 8, c = i & 255;
  qposb[i] = qe[q * 512 + c];
  float tg = qe[q * 512 + 256 + c];
  tgt[i] = tg;
  tgt[kNQ * kC + i] = tg;
}

// ---------------- ref300[q][2] = sigmoid(qpos[q] . refp_w[xy] + refp_b[xy]) ----------------
__global__ __launch_bounds__(64) void ref_k(const float* __restrict__ qposb,
                                            const float* __restrict__ rw,
                                            const float* __restrict__ rb,
                                            float* __restrict__ ref300) {
  const int q = blockIdx.x;
  const int lane = threadIdx.x;
  const float4 qv = ((const float4*)(qposb + q * 256))[lane];
  const float4 w0 = ((const float4*)rw)[lane];
  const float4 w1 = ((const float4*)(rw + 256))[lane];
  float a0 = qv.x * w0.x + qv.y * w0.y + qv.z * w0.z + qv.w * w0.w;
  float a1 = qv.x * w1.x + qv.y * w1.y + qv.z * w1.z + qv.w * w1.w;
#pragma unroll
  for (int off = 32; off; off >>= 1) {
    a0 += __shfl_xor(a0, off);
    a1 += __shfl_xor(a1, off);
  }
  if (lane == 0) {
    ref300[q * 2 + 0] = 1.f / (1.f + __expf(-(a0 + rb[0])));
    ref300[q * 2 + 1] = 1.f / (1.f + __expf(-(a1 + rb[1])));
  }
}

// ---------------- decoder self-attention, one wave per (b,h,q) ----------------
// qk:[B,NQ,512] (Q cols 0..255, K cols 256..511), v:[B,NQ,256], out:[B,NQ,256]
__global__ __launch_bounds__(64) void dec_attn_k(const float* __restrict__ qk,
                                                 const float* __restrict__ v,
                                                 float* __restrict__ outp) {
  const int bid = blockIdx.x;
  const int q = bid % kNQ;
  const int bh = bid / kNQ;
  const int h = bh & 7;
  const int b = bh >> 3;
  const int lane = threadIdx.x;
  __shared__ float p[304];
  const float* qv = qk + ((size_t)(b * kNQ + q)) * 512 + h * 32;
  float qreg[32];
#pragma unroll
  for (int m = 0; m < 32; ++m) qreg[m] = qv[m];
  float scores[5];
  float mx = -1e30f;
#pragma unroll
  for (int j = 0; j < 5; ++j) {
    const int k = lane + j * 64;
    float sc = -1e30f;
    if (k < kNQ) {
      const float* kv = qk + ((size_t)(b * kNQ + k)) * 512 + 256 + h * 32;
      float acc = 0.f;
#pragma unroll
      for (int m = 0; m < 32; ++m) acc = fmaf(qreg[m], kv[m], acc);
      sc = acc * 0.17677669529663687f;  // 1/sqrt(32)
    }
    scores[j] = sc;
    mx = fmaxf(mx, sc);
  }
#pragma unroll
  for (int off = 32; off; off >>= 1) mx = fmaxf(mx, __shfl_xor(mx, off));
  float sum = 0.f;
#pragma unroll
  for (int j = 0; j < 5; ++j) {
    const int k = lane + j * 64;
    float e = 0.f;
    if (k < kNQ) e = __expf(scores[j] - mx);
    scores[j] = e;
    sum += e;
  }
#pragma unroll
  for (int off = 32; off; off >>= 1) sum += __shfl_xor(sum, off);
  const float inv = 1.f / sum;
#pragma unroll
  for (int j = 0; j < 5; ++j) {
    const int k = lane + j * 64;
    if (k < kNQ) p[k] = scores[j] * inv;
  }
  __syncthreads();
  const int d = lane & 31, half = lane >> 5;
  float acc = 0.f;
  for (int k = half * 150; k < half * 150 + 150; ++k)
    acc = fmaf(p[k], v[((size_t)(b * kNQ + k)) * 256 + h * 32 + d], acc);
  acc += __shfl_down(acc, 32);
  if (lane < 32) outp[((size_t)(b * kNQ + q)) * 256 + h * 32 + d] = acc;
}

// ---------------- write init_ref / ref outputs ----------------
__global__ void write_refs_k(const float* __restrict__ ref300, float* __restrict__ outp) {
  int i = blockIdx.x * 256 + threadIdx.x;
  if (i >= 1200) return;
  float v = ref300[i % 600];
  outp[153600 + i] = v;
  outp[154800 + i] = v;
}

__global__ void sentinel_k(float* __restrict__ outp) {
  if (threadIdx.x < 64) outp[threadIdx.x] = 12345.0f;
}

extern "C" void kernel_launch(void* const* d_in, const int* in_sizes, int n_in,
                              void* d_out, int out_size, void* d_ws, size_t ws_size,
                              hipStream_t stream) {
  const float* src      = (const float*)d_in[0];
  const float* pos      = (const float*)d_in[1];
  const float* qe       = (const float*)d_in[2];
  const float* lev      = (const float*)d_in[3];
  const float* refp_w   = (const float*)d_in[4];
  const float* refp_b   = (const float*)d_in[5];
  const float* eso_w    = (const float*)d_in[6];
  const float* eso_b    = (const float*)d_in[7];
  const float* eaw_w    = (const float*)d_in[8];
  const float* eaw_b    = (const float*)d_in[9];
  const float* evp_w    = (const float*)d_in[10];
  const float* evp_b    = (const float*)d_in[11];
  const float* eop_w    = (const float*)d_in[12];
  const float* eop_b    = (const float*)d_in[13];
  const float* en1_g    = (const float*)d_in[14];
  const float* en1_b    = (const float*)d_in[15];
  const float* el1_w    = (const float*)d_in[16];
  const float* el1_b    = (const float*)d_in[17];
  const float* el2_w    = (const float*)d_in[18];
  const float* el2_b    = (const float*)d_in[19];
  const float* en2_g    = (const float*)d_in[20];
  const float* en2_b    = (const float*)d_in[21];
  const float* dso_w    = (const float*)d_in[22];
  const float* dso_b    = (const float*)d_in[23];
  const float* daw_w    = (const float*)d_in[24];
  const float* daw_b    = (const float*)d_in[25];
  const float* dvp_w    = (const float*)d_in[26];
  const float* dvp_b    = (const float*)d_in[27];
  const float* dop_w    = (const float*)d_in[28];
  const float* dop_b    = (const float*)d_in[29];
  const float* dsa_in_w = (const float*)d_in[30];
  const float* dsa_in_b = (const float*)d_in[31];
  const float* dsa_out_w= (const float*)d_in[32];
  const float* dsa_out_b= (const float*)d_in[33];
  const float* dn1_g    = (const float*)d_in[34];
  const float* dn1_b    = (const float*)d_in[35];
  const float* dn2_g    = (const float*)d_in[36];
  const float* dn2_b    = (const float*)d_in[37];
  const float* dn3_g    = (const float*)d_in[38];
  const float* dn3_b    = (const float*)d_in[39];
  const float* dl1_w    = (const float*)d_in[40];
  const float* dl1_b    = (const float*)d_in[41];
  const float* dl2_w    = (const float*)d_in[42];
  const float* dl2_b    = (const float*)d_in[43];

  float* Wsp = (float*)d_ws;
  size_t off = 0;
  auto alloc = [&](size_t n) { float* p = Wsp + off; off += n; return p; };
  float* memory  = alloc((size_t)kBS * kC);     // persists through decoder
  float* qbuf    = alloc((size_t)kBS * kC);     // union base (ffn hidden aliases here)
  float* valbuf  = alloc((size_t)kBS * kC);
  float* offsbuf = alloc((size_t)kBS * kC);
  float* awbuf   = alloc((size_t)kBS * 128);
  float* sampbuf = alloc((size_t)kBS * kC);
  float* msdabuf = alloc((size_t)kBS * kC);
  float* refS    = alloc((size_t)kS * 2);
  float* tgt     = alloc((size_t)kB * kNQ * kC);
  float* qposb   = alloc((size_t)kNQ * kC);
  float* dq      = alloc((size_t)kB * kNQ * kC);
  float* qkbuf   = alloc((size_t)kB * kNQ * 512);
  float* vbuf    = alloc((size_t)kB * kNQ * kC);
  float* sabuf   = alloc((size_t)kB * kNQ * kC);
  float* sa2buf  = alloc((size_t)kB * kNQ * kC);
  float* doffs   = alloc((size_t)kB * kNQ * kC);
  float* dawb    = alloc((size_t)kB * kNQ * 128);
  float* dsamp   = alloc((size_t)kB * kNQ * kC);
  float* dmsda   = alloc((size_t)kB * kNQ * kC);
  float* dffnh   = alloc((size_t)kB * kNQ * kFF);
  float* dffn    = alloc((size_t)kB * kNQ * kC);
  float* ref300  = alloc(600);
  float* ffnbuf  = qbuf;  // alias: [qbuf..sampbuf] = 30.6M floats >= BS*1024 = 27.2M

  if (ws_size < off * sizeof(float)) {
    hipLaunchKernelGGL(sentinel_k, dim3(1), dim3(64), 0, stream, (float*)d_out);
    return;
  }

  auto GEMM = [&](const float* A, const float* Wt, const float* bias, float* out,
                  int M, int N, int K, int act) {
    dim3 g(N >> 6, (M + 63) >> 6);
    if (act)
      hipLaunchKernelGGL(gemm_bias<1>, g, dim3(256), 0, stream, A, Wt, bias, out, M, N, K);
    else
      hipLaunchKernelGGL(gemm_bias<0>, g, dim3(256), 0, stream, A, Wt, bias, out, M, N, K);
  };

  // ---- setup ----
  hipMemcpyAsync(memory, src, (size_t)kBS * kC * sizeof(float),
                 hipMemcpyDeviceToDevice, stream);
  hipLaunchKernelGGL(refs_k, dim3((kS + 255) / 256), dim3(256), 0, stream, refS);

  const int n4full = kBS * 64;  // BS*C/4
  // ---- encoder ----
  for (int i = 0; i < kNL; ++i) {
    hipLaunchKernelGGL(enc_q_k, dim3((n4full + 255) / 256), dim3(256), 0, stream,
                       memory, pos, lev, qbuf, n4full);
    GEMM(memory, evp_w + (size_t)i * kC * kC, evp_b + i * kC, valbuf, kBS, 256, 256, 0);
    GEMM(qbuf, eso_w + (size_t)i * 256 * kC, eso_b + i * 256, offsbuf, kBS, 256, 256, 0);
    GEMM(qbuf, eaw_w + (size_t)i * 128 * kC, eaw_b + i * 128, awbuf, kBS, 128, 256, 0);
    hipLaunchKernelGGL(softmax16_k, dim3((kBS * 8 + 255) / 256), dim3(256), 0, stream,
                       awbuf, kBS * 8);
    hipLaunchKernelGGL(msda_sample_k, dim3(kBS), dim3(256), 0, stream,
                       valbuf, offsbuf, awbuf, refS, sampbuf, kS);
    GEMM(sampbuf, eop_w + (size_t)i * kC * kC, eop_b + i * kC, msdabuf, kBS, 256, 256, 0);
    hipLaunchKernelGGL(ln_res_k, dim3(kBS / 4), dim3(256), 0, stream,
                       memory, msdabuf, en1_g + i * kC, en1_b + i * kC, memory, kBS);
    GEMM(memory, el1_w + (size_t)i * kFF * kC, el1_b + i * kFF, ffnbuf, kBS, 1024, 256, 1);
    GEMM(ffnbuf, el2_w + (size_t)i * kC * kFF, el2_b + i * kC, msdabuf, kBS, 256, 1024, 0);
    hipLaunchKernelGGL(ln_res_k, dim3(kBS / 4), dim3(256), 0, stream,
                       memory, msdabuf, en2_g + i * kC, en2_b + i * kC, memory, kBS);
  }

  // ---- decoder init ----
  hipLaunchKernelGGL(dec_init_k, dim3(300), dim3(256), 0, stream, qe, tgt, qposb);
  hipLaunchKernelGGL(ref_k, dim3(kNQ), dim3(64), 0, stream, qposb, refp_w, refp_b, ref300);

  const int dn4 = kB * kNQ * 64;   // 2*300*256/4
  const int qn4 = kNQ * 64;        // 300*256/4
  // ---- decoder ----
  for (int i = 0; i < kNL; ++i) {
    // self-attention
    hipLaunchKernelGGL(add_bcast_k, dim3((dn4 + 255) / 256), dim3(256), 0, stream,
                       tgt, qposb, dq, dn4, qn4);
    GEMM(dq, dsa_in_w + (size_t)i * 768 * kC, dsa_in_b + i * 768, qkbuf,
         kB * kNQ, 512, 256, 0);
    GEMM(tgt, dsa_in_w + (size_t)i * 768 * kC + (size_t)512 * kC,
         dsa_in_b + i * 768 + 512, vbuf, kB * kNQ, 256, 256, 0);
    hipLaunchKernelGGL(dec_attn_k, dim3(kB * kH * kNQ), dim3(64), 0, stream,
                       qkbuf, vbuf, sabuf);
    GEMM(sabuf, dsa_out_w + (size_t)i * kC * kC, dsa_out_b + i * kC, sa2buf,
         kB * kNQ, 256, 256, 0);
    hipLaunchKernelGGL(ln_res_k, dim3((kB * kNQ + 3) / 4), dim3(256), 0, stream,
                       tgt, sa2buf, dn2_g + i * kC, dn2_b + i * kC, tgt, kB * kNQ);
    // cross-attention (MSDA)
    hipLaunchKernelGGL(add_bcast_k, dim3((dn4 + 255) / 256), dim3(256), 0, stream,
                       tgt, qposb, dq, dn4, qn4);
    GEMM(memory, dvp_w + (size_t)i * kC * kC, dvp_b + i * kC, valbuf, kBS, 256, 256, 0);
    GEMM(dq, dso_w + (size_t)i * 256 * kC, dso_b + i * 256, doffs, kB * kNQ, 256, 256, 0);
    GEMM(dq, daw_w + (size_t)i * 128 * kC, daw_b + i * 128, dawb, kB * kNQ, 128, 256, 0);
    hipLaunchKernelGGL(softmax16_k, dim3((kB * kNQ * 8 + 255) / 256), dim3(256), 0, stream,
                       dawb, kB * kNQ * 8);
    hipLaunchKernelGGL(msda_sample_k, dim3(kB * kNQ), dim3(256), 0, stream,
                       valbuf, doffs, dawb, ref300, dsamp, kNQ);
    GEMM(dsamp, dop_w + (size_t)i * kC * kC, dop_b + i * kC, dmsda, kB * kNQ, 256, 256, 0);
    hipLaunchKernelGGL(ln_res_k, dim3((kB * kNQ + 3) / 4), dim3(256), 0, stream,
                       tgt, dmsda, dn1_g + i * kC, dn1_b + i * kC, tgt, kB * kNQ);
    // FFN
    GEMM(tgt, dl1_w + (size_t)i * kFF * kC, dl1_b + i * kFF, dffnh, kB * kNQ, 1024, 256, 1);
    GEMM(dffnh, dl2_w + (size_t)i * kC * kFF, dl2_b + i * kC, dffn, kB * kNQ, 256, 1024, 0);
    hipLaunchKernelGGL(ln_res_k, dim3((kB * kNQ + 3) / 4), dim3(256), 0, stream,
                       tgt, dffn, dn3_g + i * kC, dn3_b + i * kC, tgt, kB * kNQ);
  }

  // ---- outputs: (tgt [2,300,256], init_ref [2,300,2], ref [2,300,2]) ----
  hipMemcpyAsync(d_out, tgt, (size_t)kB * kNQ * kC * sizeof(float),
                 hipMemcpyDeviceToDevice, stream);
  hipLaunchKernelGGL(write_refs_k, dim3(5), dim3(256), 0, stream, ref300, (float*)d_out);
}

// Round 2
// 2714.284 us; speedup vs baseline: 2.5866x; 2.5866x over previous
//
#include <hip/hip_runtime.h>

static constexpr int kS  = 13294;
static constexpr int kB  = 2;
static constexpr int kBS = kB * kS;     // 26588
static constexpr int kC  = 256;
static constexpr int kH  = 8;
static constexpr int kNQ = 300;
static constexpr int kFF = 1024;
static constexpr int kNL = 6;

using short8 = __attribute__((ext_vector_type(8))) short;
using f32x4  = __attribute__((ext_vector_type(4))) float;

__device__ __forceinline__ unsigned short f2b(float f) {
  unsigned u = __builtin_bit_cast(unsigned, f);
  return (unsigned short)((u + 0x7FFF + ((u >> 16) & 1)) >> 16);
}

#if defined(__has_builtin)
#if __has_builtin(__builtin_amdgcn_global_load_lds)
#define HAS_GLL 1
#endif
#endif
#ifndef HAS_GLL
#define HAS_GLL 0
#endif

#if HAS_GLL
typedef const __attribute__((address_space(1))) void* gas_t;
typedef __attribute__((address_space(3))) void* las_t;
#define GLOAD16(gp, lp) __builtin_amdgcn_global_load_lds((gas_t)(gp), (las_t)(lp), 16, 0, 0)
#endif

// ---------------- bf16 MFMA GEMM: out[M,N] = act(A[M,K] @ Wt[N,K]^T + bias[N]) ----------------
// BM=BN=128, BK=64, 256 threads = 4 waves (2x2), each wave 64x64 via 4x4 frags of 16x16x32.
template<int ACT, int OBF>
__global__ __launch_bounds__(256) void gemm_mfma(
    const unsigned short* __restrict__ A,   // [M,K] bf16
    const unsigned short* __restrict__ Wt,  // [N,K] bf16
    const float* __restrict__ bias,         // [N]
    void* __restrict__ outp,                // [M,N] f32 (OBF=0) or bf16 (OBF=1)
    int M, int N, int K) {
  __shared__ __align__(16) unsigned short As[128 * 64];
  __shared__ __align__(16) unsigned short Bs[128 * 64];
  const int t = threadIdx.x;
  const int m0 = blockIdx.y * 128, n0 = blockIdx.x * 128;
  const int wid = t >> 6, lane = t & 63;
  const int wr = wid >> 1, wc = wid & 1;
  const int srow = t >> 3;           // 0..31 (staging row within 32-row chunk)
  const int scol = (t & 7) * 8;      // staging col
  const int lr = lane & 15;
  const int lk = (lane >> 4) * 8;

  f32x4 acc[4][4];
#pragma unroll
  for (int i = 0; i < 4; ++i)
#pragma unroll
    for (int j = 0; j < 4; ++j) acc[i][j] = (f32x4){0.f, 0.f, 0.f, 0.f};

  for (int k0 = 0; k0 < K; k0 += 64) {
#if HAS_GLL
    __syncthreads();
#pragma unroll
    for (int c = 0; c < 4; ++c) {
      int ar = m0 + c * 32 + srow; if (ar >= M) ar = M - 1;
      GLOAD16(A + (size_t)ar * K + k0 + scol, (char*)As + c * 4096 + t * 16);
      int br = n0 + c * 32 + srow; if (br >= N) br = N - 1;
      GLOAD16(Wt + (size_t)br * K + k0 + scol, (char*)Bs + c * 4096 + t * 16);
    }
    __syncthreads();
#else
    short8 ta[4], tb[4];
#pragma unroll
    for (int c = 0; c < 4; ++c) {
      int ar = m0 + c * 32 + srow; if (ar >= M) ar = M - 1;
      ta[c] = *(const short8*)(A + (size_t)ar * K + k0 + scol);
      int br = n0 + c * 32 + srow; if (br >= N) br = N - 1;
      tb[c] = *(const short8*)(Wt + (size_t)br * K + k0 + scol);
    }
    __syncthreads();
#pragma unroll
    for (int c = 0; c < 4; ++c) {
      *(short8*)&As[c * 2048 + t * 8] = ta[c];
      *(short8*)&Bs[c * 2048 + t * 8] = tb[c];
    }
    __syncthreads();
#endif
#pragma unroll
    for (int kk = 0; kk < 2; ++kk) {
      short8 af[4], bf[4];
#pragma unroll
      for (int mi = 0; mi < 4; ++mi)
        af[mi] = *(const short8*)&As[(wr * 64 + mi * 16 + lr) * 64 + kk * 32 + lk];
#pragma unroll
      for (int ni = 0; ni < 4; ++ni)
        bf[ni] = *(const short8*)&Bs[(wc * 64 + ni * 16 + lr) * 64 + kk * 32 + lk];
#pragma unroll
      for (int mi = 0; mi < 4; ++mi)
#pragma unroll
        for (int ni = 0; ni < 4; ++ni)
          acc[mi][ni] = __builtin_amdgcn_mfma_f32_16x16x32_bf16(af[mi], bf[ni], acc[mi][ni], 0, 0, 0);
    }
  }
  // epilogue: C/D layout col=lane&15, row=(lane>>4)*4+j
  const int orow0 = m0 + wr * 64;
  const int ocol = n0 + wc * 64 + (lane & 15);
  float bv[4];
#pragma unroll
  for (int ni = 0; ni < 4; ++ni) bv[ni] = bias[ocol + ni * 16];
#pragma unroll
  for (int mi = 0; mi < 4; ++mi) {
#pragma unroll
    for (int j = 0; j < 4; ++j) {
      const int r = orow0 + mi * 16 + (lane >> 4) * 4 + j;
      if (r < M) {
#pragma unroll
        for (int ni = 0; ni < 4; ++ni) {
          float v = acc[mi][ni][j] + bv[ni];
          if (ACT) v = fmaxf(v, 0.f);
          if (OBF) ((unsigned short*)outp)[(size_t)r * N + ocol + ni * 16] = f2b(v);
          else     ((float*)outp)[(size_t)r * N + ocol + ni * 16] = v;
        }
      }
    }
  }
}

// ---------------- casts ----------------
__global__ void cast_bf_k(const float* __restrict__ in, unsigned short* __restrict__ out, int n4) {
  int i = blockIdx.x * 256 + threadIdx.x;
  if (i >= n4) return;
  float4 v = ((const float4*)in)[i];
  ushort4 o; o.x = f2b(v.x); o.y = f2b(v.y); o.z = f2b(v.z); o.w = f2b(v.w);
  ((ushort4*)out)[i] = o;
}

__global__ void copy_cast_k(const float* __restrict__ in, float* __restrict__ outf,
                            unsigned short* __restrict__ outb, int n4) {
  int i = blockIdx.x * 256 + threadIdx.x;
  if (i >= n4) return;
  float4 v = ((const float4*)in)[i];
  ((float4*)outf)[i] = v;
  ushort4 o; o.x = f2b(v.x); o.y = f2b(v.y); o.z = f2b(v.z); o.w = f2b(v.w);
  ((ushort4*)outb)[i] = o;
}

// ---------------- q = memory + pos + level_embed -> bf16 ----------------
__global__ void enc_q_k(const float* __restrict__ mem, const float* __restrict__ pos,
                        const float* __restrict__ lev, unsigned short* __restrict__ q, int n4) {
  int i = blockIdx.x * 256 + threadIdx.x;
  if (i >= n4) return;
  int c4 = i & 63;
  int row = i >> 6;
  int s = row % kS;
  int l = (s < 10000) ? 0 : (s < 12500) ? 1 : (s < 13125) ? 2 : 3;
  float4 m = ((const float4*)mem)[i];
  float4 p = ((const float4*)pos)[i];
  float4 lv = ((const float4*)(lev + l * kC))[c4];
  ushort4 o;
  o.x = f2b(m.x + p.x + lv.x); o.y = f2b(m.y + p.y + lv.y);
  o.z = f2b(m.z + p.z + lv.z); o.w = f2b(m.w + p.w + lv.w);
  ((ushort4*)q)[i] = o;
}

// ---------------- softmax over 16 ----------------
__global__ void softmax16_k(float* __restrict__ aw, int total) {
  int i = blockIdx.x * 256 + threadIdx.x;
  if (i >= total) return;
  float* p = aw + (size_t)i * 16;
  float v[16];
  float mx = -1e30f;
#pragma unroll
  for (int j = 0; j < 16; ++j) { v[j] = p[j]; mx = fmaxf(mx, v[j]); }
  float s = 0.f;
#pragma unroll
  for (int j = 0; j < 16; ++j) { v[j] = __expf(v[j] - mx); s += v[j]; }
  float inv = 1.f / s;
#pragma unroll
  for (int j = 0; j < 16; ++j) p[j] = v[j] * inv;
}

// ---------------- encoder reference points ----------------
__global__ void refs_k(float* __restrict__ refS) {
  int s = blockIdx.x * 256 + threadIdx.x;
  if (s >= kS) return;
  int st, W;
  if (s < 10000)      { st = 0;     W = 100; }
  else if (s < 12500) { st = 10000; W = 50; }
  else if (s < 13125) { st = 12500; W = 25; }
  else                { st = 13125; W = 13; }
  int idx = s - st;
  int y = idx / W;
  int x = idx - y * W;
  refS[s * 2 + 0] = (x + 0.5f) / (float)W;
  refS[s * 2 + 1] = (y + 0.5f) / (float)W;
}

// ---------------- MSDA sampling (branch-free, bf16 out) ----------------
__global__ __launch_bounds__(256) void msda_sample_k(
    const float* __restrict__ value, const float* __restrict__ offs,
    const float* __restrict__ aw, const float* __restrict__ refs,
    unsigned short* __restrict__ out, int Mq) {
  const int g = threadIdx.x >> 5, lane = threadIdx.x & 31;
  const long gid = (long)blockIdx.x * 8 + g;
  const long bq = gid >> 3;
  const int h = (int)(gid & 7);
  if (bq >= (long)kB * Mq) return;
  const int b = (bq >= Mq) ? 1 : 0;
  const int qi = (int)(bq - (long)b * Mq);
  const float rx = refs[qi * 2 + 0];
  const float ry = refs[qi * 2 + 1];
  const float* op = offs + (bq * 8 + h) * 32;
  const float* ap = aw + (bq * 8 + h) * 16;
  const int starts[4] = {0, 10000, 12500, 13125};
  const int wtab[4] = {100, 50, 25, 13};
  float acc = 0.f;
#pragma unroll
  for (int l = 0; l < 4; ++l) {
    const int W = wtab[l];
    const float fW = (float)W;
    const float* vb = value + ((size_t)(b * kS + starts[l])) * 256 + h * 32 + lane;
#pragma unroll
    for (int p = 0; p < 4; ++p) {
      const float a = ap[l * 4 + p];
      const float px = fmaf(rx, fW, op[(l * 4 + p) * 2 + 0]) - 0.5f;
      const float py = fmaf(ry, fW, op[(l * 4 + p) * 2 + 1]) - 0.5f;
      const float fx = floorf(px), fy = floorf(py);
      const float wx = px - fx, wy = py - fy;
      const int x0 = (int)fx, y0 = (int)fy;
      const int x0c = min(max(x0, 0), W - 1);
      const int x1c = min(max(x0 + 1, 0), W - 1);
      const int y0c = min(max(y0, 0), W - 1);
      const int y1c = min(max(y0 + 1, 0), W - 1);
      const float vx0 = (x0 >= 0 && x0 < W) ? 1.f : 0.f;
      const float vx1 = (x0 + 1 < W) ? 1.f : 0.f;   // x0+1 >= 0 iff x0 >= -1; if x0<-1 then wx... x0+1<0 => clamp+vx1 math
      const float vx1b = (x0 + 1 >= 0) ? vx1 : 0.f;
      const float vy0 = (y0 >= 0 && y0 < W) ? 1.f : 0.f;
      const float vy1 = (y0 + 1 >= 0 && y0 + 1 < W) ? 1.f : 0.f;
      const float v00 = vb[(y0c * W + x0c) * 256];
      const float v01 = vb[(y0c * W + x1c) * 256];
      const float v10 = vb[(y1c * W + x0c) * 256];
      const float v11 = vb[(y1c * W + x1c) * 256];
      const float omwx = 1.f - wx, omwy = 1.f - wy;
      acc += a * (omwy * (omwx * v00 * vy0 * vx0 + wx * v01 * vy0 * vx1b) +
                  wy * (omwx * v10 * vy1 * vx0 + wx * v11 * vy1 * vx1b));
    }
  }
  out[(bq * 8 + h) * 32 + lane] = f2b(acc);
}

// ---------------- LayerNorm(x + y): dual fp32 + bf16 out ----------------
__global__ __launch_bounds__(256) void ln_res_k(
    const float* __restrict__ x, const float* __restrict__ y,
    const float* __restrict__ g, const float* __restrict__ be,
    float* __restrict__ out, unsigned short* __restrict__ out_bf, int rows) {
  const int wid = threadIdx.x >> 6;
  const int lane = threadIdx.x & 63;
  const int row = blockIdx.x * 4 + wid;
  if (row >= rows) return;
  const float4 a = ((const float4*)(x + (size_t)row * 256))[lane];
  const float4 b = ((const float4*)(y + (size_t)row * 256))[lane];
  const float v0 = a.x + b.x, v1 = a.y + b.y, v2 = a.z + b.z, v3 = a.w + b.w;
  float s = v0 + v1 + v2 + v3;
  float s2 = v0 * v0 + v1 * v1 + v2 * v2 + v3 * v3;
#pragma unroll
  for (int off = 32; off; off >>= 1) {
    s += __shfl_xor(s, off);
    s2 += __shfl_xor(s2, off);
  }
  const float mean = s * (1.f / 256.f);
  const float var = s2 * (1.f / 256.f) - mean * mean;
  const float r = rsqrtf(var + 1e-5f);
  const float4 gg = ((const float4*)g)[lane];
  const float4 bb = ((const float4*)be)[lane];
  float4 o;
  o.x = (v0 - mean) * r * gg.x + bb.x;
  o.y = (v1 - mean) * r * gg.y + bb.y;
  o.z = (v2 - mean) * r * gg.z + bb.z;
  o.w = (v3 - mean) * r * gg.w + bb.w;
  ((float4*)(out + (size_t)row * 256))[lane] = o;
  ushort4 ob; ob.x = f2b(o.x); ob.y = f2b(o.y); ob.z = f2b(o.z); ob.w = f2b(o.w);
  ((ushort4*)(out_bf + (size_t)row * 256))[lane] = ob;
}

// ---------------- out_bf = bf16(a + b[i % nb]) ----------------
__global__ void add_bcast_bf_k(const float* __restrict__ a, const float* __restrict__ b,
                               unsigned short* __restrict__ out, int n4, int nb4) {
  int i = blockIdx.x * 256 + threadIdx.x;
  if (i >= n4) return;
  const float4 av = ((const float4*)a)[i];
  const float4 bv = ((const float4*)b)[i % nb4];
  ushort4 o;
  o.x = f2b(av.x + bv.x); o.y = f2b(av.y + bv.y);
  o.z = f2b(av.z + bv.z); o.w = f2b(av.w + bv.w);
  ((ushort4*)out)[i] = o;
}

// ---------------- decoder init ----------------
__global__ void dec_init_k(const float* __restrict__ qe, float* __restrict__ tgt,
                           unsigned short* __restrict__ tgt_bf, float* __restrict__ qposb) {
  int i = blockIdx.x * 256 + threadIdx.x;
  if (i >= kNQ * kC) return;
  int q = i >> 8, c = i & 255;
  qposb[i] = qe[q * 512 + c];
  float tg = qe[q * 512 + 256 + c];
  tgt[i] = tg;
  tgt[kNQ * kC + i] = tg;
  unsigned short tb = f2b(tg);
  tgt_bf[i] = tb;
  tgt_bf[kNQ * kC + i] = tb;
}

// ---------------- ref300 = sigmoid(qpos @ refp_w^T + refp_b) ----------------
__global__ __launch_bounds__(64) void ref_k(const float* __restrict__ qposb,
                                            const float* __restrict__ rw,
                                            const float* __restrict__ rb,
                                            float* __restrict__ ref300) {
  const int q = blockIdx.x;
  const int lane = threadIdx.x;
  const float4 qv = ((const float4*)(qposb + q * 256))[lane];
  const float4 w0 = ((const float4*)rw)[lane];
  const float4 w1 = ((const float4*)(rw + 256))[lane];
  float a0 = qv.x * w0.x + qv.y * w0.y + qv.z * w0.z + qv.w * w0.w;
  float a1 = qv.x * w1.x + qv.y * w1.y + qv.z * w1.z + qv.w * w1.w;
#pragma unroll
  for (int off = 32; off; off >>= 1) {
    a0 += __shfl_xor(a0, off);
    a1 += __shfl_xor(a1, off);
  }
  if (lane == 0) {
    ref300[q * 2 + 0] = 1.f / (1.f + __expf(-(a0 + rb[0])));
    ref300[q * 2 + 1] = 1.f / (1.f + __expf(-(a1 + rb[1])));
  }
}

// ---------------- decoder self-attention (bf16 out) ----------------
__global__ __launch_bounds__(64) void dec_attn_k(const float* __restrict__ qk,
                                                 const float* __restrict__ v,
                                                 unsigned short* __restrict__ outp) {
  const int bid = blockIdx.x;
  const int q = bid % kNQ;
  const int bh = bid / kNQ;
  const int h = bh & 7;
  const int b = bh >> 3;
  const int lane = threadIdx.x;
  __shared__ float p[304];
  const float* qv = qk + ((size_t)(b * kNQ + q)) * 512 + h * 32;
  float qreg[32];
#pragma unroll
  for (int m = 0; m < 32; ++m) qreg[m] = qv[m];
  float scores[5];
  float mx = -1e30f;
#pragma unroll
  for (int j = 0; j < 5; ++j) {
    const int k = lane + j * 64;
    float sc = -1e30f;
    if (k < kNQ) {
      const float* kv = qk + ((size_t)(b * kNQ + k)) * 512 + 256 + h * 32;
      float acc = 0.f;
#pragma unroll
      for (int m = 0; m < 32; ++m) acc = fmaf(qreg[m], kv[m], acc);
      sc = acc * 0.17677669529663687f;
    }
    scores[j] = sc;
    mx = fmaxf(mx, sc);
  }
#pragma unroll
  for (int off = 32; off; off >>= 1) mx = fmaxf(mx, __shfl_xor(mx, off));
  float sum = 0.f;
#pragma unroll
  for (int j = 0; j < 5; ++j) {
    const int k = lane + j * 64;
    float e = 0.f;
    if (k < kNQ) e = __expf(scores[j] - mx);
    scores[j] = e;
    sum += e;
  }
#pragma unroll
  for (int off = 32; off; off >>= 1) sum += __shfl_xor(sum, off);
  const float inv = 1.f / sum;
#pragma unroll
  for (int j = 0; j < 5; ++j) {
    const int k = lane + j * 64;
    if (k < kNQ) p[k] = scores[j] * inv;
  }
  __syncthreads();
  const int d = lane & 31, half = lane >> 5;
  float acc = 0.f;
  for (int k = half * 150; k < half * 150 + 150; ++k)
    acc = fmaf(p[k], v[((size_t)(b * kNQ + k)) * 256 + h * 32 + d], acc);
  acc += __shfl_down(acc, 32);
  if (lane < 32) outp[((size_t)(b * kNQ + q)) * 256 + h * 32 + d] = f2b(acc);
}

// ---------------- write init_ref / ref outputs ----------------
__global__ void write_refs_k(const float* __restrict__ ref300, float* __restrict__ outp) {
  int i = blockIdx.x * 256 + threadIdx.x;
  if (i >= 1200) return;
  float v = ref300[i % 600];
  outp[153600 + i] = v;
  outp[154800 + i] = v;
}

__global__ void sentinel_k(float* __restrict__ outp) {
  if (threadIdx.x < 64) outp[threadIdx.x] = 12345.0f;
}

extern "C" void kernel_launch(void* const* d_in, const int* in_sizes, int n_in,
                              void* d_out, int out_size, void* d_ws, size_t ws_size,
                              hipStream_t stream) {
  const float* src      = (const float*)d_in[0];
  const float* pos      = (const float*)d_in[1];
  const float* qe       = (const float*)d_in[2];
  const float* lev      = (const float*)d_in[3];
  const float* refp_w   = (const float*)d_in[4];
  const float* refp_b   = (const float*)d_in[5];
  const float* eso_w    = (const float*)d_in[6];
  const float* eso_b    = (const float*)d_in[7];
  const float* eaw_w    = (const float*)d_in[8];
  const float* eaw_b    = (const float*)d_in[9];
  const float* evp_w    = (const float*)d_in[10];
  const float* evp_b    = (const float*)d_in[11];
  const float* eop_w    = (const float*)d_in[12];
  const float* eop_b    = (const float*)d_in[13];
  const float* en1_g    = (const float*)d_in[14];
  const float* en1_b    = (const float*)d_in[15];
  const float* el1_w    = (const float*)d_in[16];
  const float* el1_b    = (const float*)d_in[17];
  const float* el2_w    = (const float*)d_in[18];
  const float* el2_b    = (const float*)d_in[19];
  const float* en2_g    = (const float*)d_in[20];
  const float* en2_b    = (const float*)d_in[21];
  const float* dso_w    = (const float*)d_in[22];
  const float* dso_b    = (const float*)d_in[23];
  const float* daw_w    = (const float*)d_in[24];
  const float* daw_b    = (const float*)d_in[25];
  const float* dvp_w    = (const float*)d_in[26];
  const float* dvp_b    = (const float*)d_in[27];
  const float* dop_w    = (const float*)d_in[28];
  const float* dop_b    = (const float*)d_in[29];
  const float* dsa_in_w = (const float*)d_in[30];
  const float* dsa_in_b = (const float*)d_in[31];
  const float* dsa_out_w= (const float*)d_in[32];
  const float* dsa_out_b= (const float*)d_in[33];
  const float* dn1_g    = (const float*)d_in[34];
  const float* dn1_b    = (const float*)d_in[35];
  const float* dn2_g    = (const float*)d_in[36];
  const float* dn2_b    = (const float*)d_in[37];
  const float* dn3_g    = (const float*)d_in[38];
  const float* dn3_b    = (const float*)d_in[39];
  const float* dl1_w    = (const float*)d_in[40];
  const float* dl1_b    = (const float*)d_in[41];
  const float* dl2_w    = (const float*)d_in[42];
  const float* dl2_b    = (const float*)d_in[43];

  float* Wsp = (float*)d_ws;
  size_t off = 0;
  auto alloc = [&](size_t n) { float* p = Wsp + off; off += n; return p; };
  const size_t NBC = (size_t)kBS * kC;           // 6,806,528
  float* memory   = alloc(NBC);
  unsigned short* memory_bf = (unsigned short*)alloc(NBC / 2);
  // regionA: valbuf + offsbuf; hid_bf aliases whole region; msdabuf aliases offsbuf
  float* valbuf   = alloc(NBC);
  float* offsbuf  = alloc(NBC);
  unsigned short* hid_bf = (unsigned short*)valbuf;   // kBS*1024 bf16 = 2*NBC fu? -> exactly 2*NBC elems = NBC fu*2... fits valbuf+offsbuf
  float* msdabuf  = offsbuf;
  // regionB: qbuf_bf + awbuf; ffn2out aliases whole region
  unsigned short* qbuf_bf = (unsigned short*)alloc(NBC / 2);
  float* awbuf    = alloc((size_t)kBS * 128);
  float* ffn2out  = (float*)qbuf_bf;
  unsigned short* sampbuf_bf = (unsigned short*)alloc(NBC / 2);
  float* refS     = alloc((size_t)kS * 2 + 2);
  // bf16 weights
  auto allocb = [&](size_t elems) { return (unsigned short*)alloc(elems / 2); };
  unsigned short* esoW  = allocb((size_t)kNL * 256 * 256);
  unsigned short* eawW  = allocb((size_t)kNL * 128 * 256);
  unsigned short* evpW  = allocb((size_t)kNL * 256 * 256);
  unsigned short* eopW  = allocb((size_t)kNL * 256 * 256);
  unsigned short* el1W  = allocb((size_t)kNL * 1024 * 256);
  unsigned short* el2W  = allocb((size_t)kNL * 256 * 1024);
  unsigned short* dsoW  = allocb((size_t)kNL * 256 * 256);
  unsigned short* dawW  = allocb((size_t)kNL * 128 * 256);
  unsigned short* dvpW  = allocb((size_t)kNL * 256 * 256);
  unsigned short* dopW  = allocb((size_t)kNL * 256 * 256);
  unsigned short* dsaiW = allocb((size_t)kNL * 768 * 256);
  unsigned short* dsaoW = allocb((size_t)kNL * 256 * 256);
  unsigned short* dl1W  = allocb((size_t)kNL * 1024 * 256);
  unsigned short* dl2W  = allocb((size_t)kNL * 256 * 1024);
  // decoder buffers
  const size_t NQC = (size_t)kB * kNQ * kC;       // 153,600
  float* tgt      = alloc(NQC);
  unsigned short* tgt_bf = (unsigned short*)alloc(NQC / 2);
  float* qposb    = alloc((size_t)kNQ * kC);
  unsigned short* dq_bf = (unsigned short*)alloc(NQC / 2);
  float* qkbuf    = alloc(NQC * 2);
  float* vbuf     = alloc(NQC);
  unsigned short* sabuf_bf = (unsigned short*)alloc(NQC / 2);
  float* sa2buf   = alloc(NQC);
  float* doffs    = alloc(NQC);
  float* dawb     = alloc((size_t)kB * kNQ * 128);
  unsigned short* dsamp_bf = (unsigned short*)alloc(NQC / 2);
  float* dmsda    = alloc(NQC);
  unsigned short* dffnh_bf = (unsigned short*)alloc((size_t)kB * kNQ * kFF / 2);
  float* dffn     = alloc(NQC);
  float* ref300   = alloc(600);

  if (ws_size < off * sizeof(float)) {
    hipLaunchKernelGGL(sentinel_k, dim3(1), dim3(64), 0, stream, (float*)d_out);
    return;
  }

  auto GEMM = [&](const unsigned short* A, const unsigned short* Wt, const float* bias,
                  void* out, int M, int N, int K, int relu_bf) {
    dim3 g(N / 128, (M + 127) / 128);
    if (relu_bf)
      hipLaunchKernelGGL((gemm_mfma<1, 1>), g, dim3(256), 0, stream, A, Wt, bias, out, M, N, K);
    else
      hipLaunchKernelGGL((gemm_mfma<0, 0>), g, dim3(256), 0, stream, A, Wt, bias, out, M, N, K);
  };
  auto CASTW = [&](const float* srcw, unsigned short* dstw, size_t elems) {
    int n4 = (int)(elems / 4);
    hipLaunchKernelGGL(cast_bf_k, dim3((n4 + 255) / 256), dim3(256), 0, stream, srcw, dstw, n4);
  };

  // ---- setup: weight casts + memory init + ref tables ----
  CASTW(eso_w, esoW, (size_t)kNL * 65536);
  CASTW(eaw_w, eawW, (size_t)kNL * 32768);
  CASTW(evp_w, evpW, (size_t)kNL * 65536);
  CASTW(eop_w, eopW, (size_t)kNL * 65536);
  CASTW(el1_w, el1W, (size_t)kNL * 262144);
  CASTW(el2_w, el2W, (size_t)kNL * 262144);
  CASTW(dso_w, dsoW, (size_t)kNL * 65536);
  CASTW(daw_w, dawW, (size_t)kNL * 32768);
  CASTW(dvp_w, dvpW, (size_t)kNL * 65536);
  CASTW(dop_w, dopW, (size_t)kNL * 65536);
  CASTW(dsa_in_w, dsaiW, (size_t)kNL * 196608);
  CASTW(dsa_out_w, dsaoW, (size_t)kNL * 65536);
  CASTW(dl1_w, dl1W, (size_t)kNL * 262144);
  CASTW(dl2_w, dl2W, (size_t)kNL * 262144);
  const int n4full = kBS * 64;
  hipLaunchKernelGGL(copy_cast_k, dim3((n4full + 255) / 256), dim3(256), 0, stream,
                     src, memory, memory_bf, n4full);
  hipLaunchKernelGGL(refs_k, dim3((kS + 255) / 256), dim3(256), 0, stream, refS);

  // ---- encoder ----
  for (int i = 0; i < kNL; ++i) {
    hipLaunchKernelGGL(enc_q_k, dim3((n4full + 255) / 256), dim3(256), 0, stream,
                       memory, pos, lev, qbuf_bf, n4full);
    GEMM(memory_bf, evpW + (size_t)i * 65536, evp_b + i * kC, valbuf, kBS, 256, 256, 0);
    GEMM(qbuf_bf, esoW + (size_t)i * 65536, eso_b + i * 256, offsbuf, kBS, 256, 256, 0);
    GEMM(qbuf_bf, eawW + (size_t)i * 32768, eaw_b + i * 128, awbuf, kBS, 128, 256, 0);
    hipLaunchKernelGGL(softmax16_k, dim3((kBS * 8 + 255) / 256), dim3(256), 0, stream,
                       awbuf, kBS * 8);
    hipLaunchKernelGGL(msda_sample_k, dim3(kBS), dim3(256), 0, stream,
                       valbuf, offsbuf, awbuf, refS, sampbuf_bf, kS);
    GEMM(sampbuf_bf, eopW + (size_t)i * 65536, eop_b + i * kC, msdabuf, kBS, 256, 256, 0);
    hipLaunchKernelGGL(ln_res_k, dim3(kBS / 4), dim3(256), 0, stream,
                       memory, msdabuf, en1_g + i * kC, en1_b + i * kC, memory, memory_bf, kBS);
    GEMM(memory_bf, el1W + (size_t)i * 262144, el1_b + i * kFF, hid_bf, kBS, 1024, 256, 1);
    GEMM(hid_bf, el2W + (size_t)i * 262144, el2_b + i * kC, ffn2out, kBS, 256, 1024, 0);
    hipLaunchKernelGGL(ln_res_k, dim3(kBS / 4), dim3(256), 0, stream,
                       memory, ffn2out, en2_g + i * kC, en2_b + i * kC, memory, memory_bf, kBS);
  }

  // ---- decoder init ----
  hipLaunchKernelGGL(dec_init_k, dim3(300), dim3(256), 0, stream, qe, tgt, tgt_bf, qposb);
  hipLaunchKernelGGL(ref_k, dim3(kNQ), dim3(64), 0, stream, qposb, refp_w, refp_b, ref300);

  const int dn4 = kB * kNQ * 64;
  const int qn4 = kNQ * 64;
  // ---- decoder ----
  for (int i = 0; i < kNL; ++i) {
    hipLaunchKernelGGL(add_bcast_bf_k, dim3((dn4 + 255) / 256), dim3(256), 0, stream,
                       tgt, qposb, dq_bf, dn4, qn4);
    GEMM(dq_bf, dsaiW + (size_t)i * 196608, dsa_in_b + i * 768, qkbuf, kB * kNQ, 512, 256, 0);
    GEMM(tgt_bf, dsaiW + (size_t)i * 196608 + (size_t)512 * 256,
         dsa_in_b + i * 768 + 512, vbuf, kB * kNQ, 256, 256, 0);
    hipLaunchKernelGGL(dec_attn_k, dim3(kB * kH * kNQ), dim3(64), 0, stream,
                       qkbuf, vbuf, sabuf_bf);
    GEMM(sabuf_bf, dsaoW + (size_t)i * 65536, dsa_out_b + i * kC, sa2buf, kB * kNQ, 256, 256, 0);
    hipLaunchKernelGGL(ln_res_k, dim3((kB * kNQ + 3) / 4), dim3(256), 0, stream,
                       tgt, sa2buf, dn2_g + i * kC, dn2_b + i * kC, tgt, tgt_bf, kB * kNQ);
    hipLaunchKernelGGL(add_bcast_bf_k, dim3((dn4 + 255) / 256), dim3(256), 0, stream,
                       tgt, qposb, dq_bf, dn4, qn4);
    GEMM(memory_bf, dvpW + (size_t)i * 65536, dvp_b + i * kC, valbuf, kBS, 256, 256, 0);
    GEMM(dq_bf, dsoW + (size_t)i * 65536, dso_b + i * 256, doffs, kB * kNQ, 256, 256, 0);
    GEMM(dq_bf, dawW + (size_t)i * 32768, daw_b + i * 128, dawb, kB * kNQ, 128, 256, 0);
    hipLaunchKernelGGL(softmax16_k, dim3((kB * kNQ * 8 + 255) / 256), dim3(256), 0, stream,
                       dawb, kB * kNQ * 8);
    hipLaunchKernelGGL(msda_sample_k, dim3(kB * kNQ), dim3(256), 0, stream,
                       valbuf, doffs, dawb, ref300, dsamp_bf, kNQ);
    GEMM(dsamp_bf, dopW + (size_t)i * 65536, dop_b + i * kC, dmsda, kB * kNQ, 256, 256, 0);
    hipLaunchKernelGGL(ln_res_k, dim3((kB * kNQ + 3) / 4), dim3(256), 0, stream,
                       tgt, dmsda, dn1_g + i * kC, dn1_b + i * kC, tgt, tgt_bf, kB * kNQ);
    GEMM(tgt_bf, dl1W + (size_t)i * 262144, dl1_b + i * kFF, dffnh_bf, kB * kNQ, 1024, 256, 1);
    GEMM(dffnh_bf, dl2W + (size_t)i * 262144, dl2_b + i * kC, dffn, kB * kNQ, 256, 1024, 0);
    hipLaunchKernelGGL(ln_res_k, dim3((kB * kNQ + 3) / 4), dim3(256), 0, stream,
                       tgt, dffn, dn3_g + i * kC, dn3_b + i * kC, tgt, tgt_bf, kB * kNQ);
  }

  hipMemcpyAsync(d_out, tgt, NQC * sizeof(float), hipMemcpyDeviceToDevice, stream);
  hipLaunchKernelGGL(write_refs_k, dim3(5), dim3(256), 0, stream, ref300, (float*)d_out);
}